// Round 4
// baseline (3318.855 us; speedup 1.0000x reference)
//
#include <hip/hip_runtime.h>
#include <math.h>

#define G 32
#define IMG_W 512
#define IMG_H 512
#define NPIX (IMG_W * IMG_H)
#define NIMG 128
#define BANDS 8
#define BAND_ROWS 64   // 8 bands per image, 1024 blocks total

__device__ __forceinline__ int quantize(float v) {
    int q = (int)(v * 31.0f);   // matches (img*31).astype(int32): RN multiply, trunc convert
    return q > 31 ? 31 : q;
}

// 1024 blocks = 128 images x 8 row-bands, 512 threads (8 waves).
// img = blk % 128 so an image's 8 bands land on one XCD (round-robin heuristic).
// Wave w owns rows [band*64 + w*8, +8); lane l owns cols [8l, 8l+8).
// Angles 0,1 accumulate in an 8KB LDS histogram (DS pipe); angles 2,3 go
// straight to the per-image global histogram via L2 atomics (VMEM pipe).
__global__ __launch_bounds__(512) void glcm_hist_kernel(
    const float* __restrict__ x, const float* __restrict__ y,
    unsigned int* __restrict__ ghist)
{
    __shared__ unsigned int hist[2 * G * G];   // 8 KB: angle0, angle1

    const int blk = blockIdx.x;
    const int img = blk & 127;          // blk % 128
    const int band = blk >> 7;          // blk / 128
    const float* base = (img < 64) ? (x + (size_t)img * NPIX)
                                   : (y + (size_t)(img - 64) * NPIX);
    const int t = threadIdx.x;

    #pragma unroll
    for (int k = 0; k < 4; ++k) hist[t + k * 512] = 0u;
    __syncthreads();

    unsigned int* h0 = hist;            // angle (0,1)
    unsigned int* h1 = hist + 1024;     // angle (1,1)
    unsigned int* gh = ghist + (size_t)img * 4096;
    unsigned int* g2 = gh + 2048;       // angle (1,0)
    unsigned int* g3 = gh + 3072;       // angle (1,-1)

    const int wave = t >> 6, lane = t & 63;
    const int r0 = band * BAND_ROWS + wave * 8;
    const float* rowp = base + (size_t)r0 * IMG_W + lane * 8;

    int qc[8];
    {
        const float4 f0 = *reinterpret_cast<const float4*>(rowp);
        const float4 f1 = *reinterpret_cast<const float4*>(rowp + 4);
        qc[0] = quantize(f0.x); qc[1] = quantize(f0.y);
        qc[2] = quantize(f0.z); qc[3] = quantize(f0.w);
        qc[4] = quantize(f1.x); qc[5] = quantize(f1.y);
        qc[6] = quantize(f1.z); qc[7] = quantize(f1.w);
    }

    for (int r = r0; r < r0 + 8; ++r) {
        const bool havenext = (r + 1 < IMG_H);
        // horizontal pairs on current row (angle 0, LDS)
        const int nx0 = __shfl_down(qc[0], 1);
        #pragma unroll
        for (int k = 0; k < 7; ++k)
            atomicAdd(&h0[qc[k] * G + qc[k + 1]], 1u);
        if (lane < 63) atomicAdd(&h0[qc[7] * G + nx0], 1u);

        if (havenext) {
            rowp += IMG_W;
            int qn[8];
            const float4 f0 = *reinterpret_cast<const float4*>(rowp);
            const float4 f1 = *reinterpret_cast<const float4*>(rowp + 4);
            qn[0] = quantize(f0.x); qn[1] = quantize(f0.y);
            qn[2] = quantize(f0.z); qn[3] = quantize(f0.w);
            qn[4] = quantize(f1.x); qn[5] = quantize(f1.y);
            qn[6] = quantize(f1.z); qn[7] = quantize(f1.w);

            const int nqn0 = __shfl_down(qn[0], 1);   // next lane's qn[0]
            const int pqn7 = __shfl_up(qn[7], 1);     // prev lane's qn[7]
            // diag (1,1) (angle 1, LDS)
            #pragma unroll
            for (int k = 0; k < 7; ++k)
                atomicAdd(&h1[qc[k] * G + qn[k + 1]], 1u);
            if (lane < 63) atomicAdd(&h1[qc[7] * G + nqn0], 1u);
            // vertical (angle 2, global/L2)
            #pragma unroll
            for (int k = 0; k < 8; ++k)
                atomicAdd(&g2[qc[k] * G + qn[k]], 1u);
            // diag (1,-1) (angle 3, global/L2)
            #pragma unroll
            for (int k = 1; k < 8; ++k)
                atomicAdd(&g3[qc[k] * G + qn[k - 1]], 1u);
            if (lane > 0) atomicAdd(&g3[qc[0] * G + pqn7], 1u);

            #pragma unroll
            for (int k = 0; k < 8; ++k) qc[k] = qn[k];
        }
    }
    __syncthreads();

    // merge LDS angles 0,1 into the per-image global histogram
    #pragma unroll
    for (int k = 0; k < 4; ++k) {
        const unsigned int v = hist[t + k * 512];
        if (v) atomicAdd(&gh[t + k * 512], v);
    }
}

// One block per image: reduce the 3 features per angle from the merged
// global histogram; write 12 floats per image.
__global__ __launch_bounds__(1024) void glcm_feat_kernel(
    const unsigned int* __restrict__ ghist, float* __restrict__ feats)
{
    __shared__ float red[4][16][3];
    const int img = blockIdx.x;
    const int t = threadIdx.x;
    const unsigned int* gh = ghist + (size_t)img * 4096;

    const int i = t >> 5, j = t & 31;
    const int d2 = (i - j) * (i - j);
    const float inv = 1.0f / (1.0f + (float)d2);
    const int lane = t & 63, wave = t >> 6;
    #pragma unroll
    for (int a = 0; a < 4; ++a) {
        const float h  = (float)gh[a * 1024 + i * G + j];
        const float ht = (float)gh[a * 1024 + j * G + i];
        float cs = h * (float)d2;
        float hs = h * inv;
        float es = (h + ht) * (h + ht);
        #pragma unroll
        for (int off = 32; off; off >>= 1) {
            cs += __shfl_down(cs, off);
            hs += __shfl_down(hs, off);
            es += __shfl_down(es, off);
        }
        if (lane == 0) { red[a][wave][0] = cs; red[a][wave][1] = hs; red[a][wave][2] = es; }
    }
    __syncthreads();
    if (t < 4) {
        float cs = 0.f, hs = 0.f, es = 0.f;
        for (int w = 0; w < 16; ++w) {
            cs += red[t][w][0]; hs += red[t][w][1]; es += red[t][w][2];
        }
        // pair counts: (0,1):512*511, (1,1):511*511, (1,0):511*512, (1,-1):511*511
        const float Na = (t == 0 || t == 2) ? 261632.0f : 261121.0f;
        float* o = feats + img * 12 + t * 3;
        o[0] = cs / Na;                    // contrast
        o[1] = sqrtf(es) / (2.0f * Na);    // energy
        o[2] = hs / Na;                    // homogeneity
    }
}

__global__ void loss_kernel(const float* __restrict__ feats, float* __restrict__ out)
{
    const int t = threadIdx.x;  // 256 threads
    float s = 0.0f;
    for (int k = t; k < 768; k += 256)
        s += fabsf(feats[k] - feats[768 + k]);
    #pragma unroll
    for (int off = 32; off; off >>= 1) s += __shfl_down(s, off);
    __shared__ float red[4];
    if ((t & 63) == 0) red[t >> 6] = s;
    __syncthreads();
    if (t == 0) out[0] = (red[0] + red[1] + red[2] + red[3]) * (1.0f / 768.0f);
}

extern "C" void kernel_launch(void* const* d_in, const int* in_sizes, int n_in,
                              void* d_out, int out_size, void* d_ws, size_t ws_size,
                              hipStream_t stream) {
    const float* x = (const float*)d_in[0];
    const float* y = (const float*)d_in[1];
    unsigned int* ghist = (unsigned int*)d_ws;                 // 128*4096*4 = 2 MB
    float* feats = (float*)((char*)d_ws + NIMG * 4096 * 4);    // 6 KB
    float* out = (float*)d_out;

    hipMemsetAsync(ghist, 0, (size_t)NIMG * 4096 * 4, stream);
    hipLaunchKernelGGL(glcm_hist_kernel, dim3(NIMG * BANDS), dim3(512), 0, stream,
                       x, y, ghist);
    hipLaunchKernelGGL(glcm_feat_kernel, dim3(NIMG), dim3(1024), 0, stream,
                       ghist, feats);
    hipLaunchKernelGGL(loss_kernel, dim3(1), dim3(256), 0, stream, feats, out);
}

// Round 5
// 53.463 us; speedup vs baseline: 62.0774x; 62.0774x over previous
//
#include <hip/hip_runtime.h>
#include <math.h>

#define G 32
#define IMG_W 512
#define IMG_H 512
#define NPIX (IMG_W * IMG_H)
#define NIMG 128
#define BAND_ROWS 128   // 4 bands per image, 512 blocks total

__device__ __forceinline__ int quantize(float v) {
    int q = (int)(v * 31.0f);   // matches (img*31).astype(int32): RN multiply, trunc convert
    return q > 31 ? 31 : q;
}

// 512 blocks = 128 images x 4 row-bands, 1024 threads (16 waves).
// Wave w owns rows [band*128 + w*8, +8); lane l owns cols [8l, 8l+8).
// Histograms: 4 angles x 1024 bins x 8 lane-copies, 16-bit packed counters
// (64 KB LDS). Copy index in the low bank bits spreads each 16-lane group
// over 8 banks and nearly eliminates same-address RMW collisions.
// word(angle,bin,lane) = angle*4096 + bin*4 + ((lane>>1)&3); add 1 or 1<<16.
__global__ __launch_bounds__(1024) void glcm_hist_kernel(
    const float* __restrict__ x, const float* __restrict__ y,
    unsigned int* __restrict__ ghist)
{
    __shared__ unsigned int hist[4 * 1024 * 4];   // 64 KB

    const int blk = blockIdx.x;
    const int img = blk >> 2;
    const int band = blk & 3;
    const float* base = (img < 64) ? (x + (size_t)img * NPIX)
                                   : (y + (size_t)(img - 64) * NPIX);
    const int t = threadIdx.x;

    #pragma unroll
    for (int k = 0; k < 16; ++k) hist[t + k * 1024] = 0u;
    __syncthreads();

    const int wave = t >> 6, lane = t & 63;
    const unsigned int whalf = (lane >> 1) & 3;          // word-within-bin
    const unsigned int hval = (lane & 1) ? 0x10000u : 1u; // 16-bit half select
    unsigned int* h0 = hist + whalf;            // angle (0,1)
    unsigned int* h1 = hist + 4096 + whalf;     // angle (1,1)
    unsigned int* h2 = hist + 8192 + whalf;     // angle (1,0)
    unsigned int* h3 = hist + 12288 + whalf;    // angle (1,-1)

    const int r0 = band * BAND_ROWS + wave * 8;
    const float* rowp = base + (size_t)r0 * IMG_W + lane * 8;

    int qc[8];
    {
        const float4 f0 = *reinterpret_cast<const float4*>(rowp);
        const float4 f1 = *reinterpret_cast<const float4*>(rowp + 4);
        qc[0] = quantize(f0.x); qc[1] = quantize(f0.y);
        qc[2] = quantize(f0.z); qc[3] = quantize(f0.w);
        qc[4] = quantize(f1.x); qc[5] = quantize(f1.y);
        qc[6] = quantize(f1.z); qc[7] = quantize(f1.w);
    }

    for (int r = r0; r < r0 + 8; ++r) {
        const bool havenext = (r + 1 < IMG_H);
        // horizontal pairs on current row (angle 0)
        const int nx0 = __shfl_down(qc[0], 1);
        #pragma unroll
        for (int k = 0; k < 7; ++k)
            atomicAdd(&h0[(qc[k] * G + qc[k + 1]) << 2], hval);
        if (lane < 63) atomicAdd(&h0[(qc[7] * G + nx0) << 2], hval);

        if (havenext) {
            rowp += IMG_W;
            int qn[8];
            const float4 f0 = *reinterpret_cast<const float4*>(rowp);
            const float4 f1 = *reinterpret_cast<const float4*>(rowp + 4);
            qn[0] = quantize(f0.x); qn[1] = quantize(f0.y);
            qn[2] = quantize(f0.z); qn[3] = quantize(f0.w);
            qn[4] = quantize(f1.x); qn[5] = quantize(f1.y);
            qn[6] = quantize(f1.z); qn[7] = quantize(f1.w);

            const int nqn0 = __shfl_down(qn[0], 1);   // next lane's qn[0]
            const int pqn7 = __shfl_up(qn[7], 1);     // prev lane's qn[7]
            // diag (1,1) (angle 1)
            #pragma unroll
            for (int k = 0; k < 7; ++k)
                atomicAdd(&h1[(qc[k] * G + qn[k + 1]) << 2], hval);
            if (lane < 63) atomicAdd(&h1[(qc[7] * G + nqn0) << 2], hval);
            // vertical (angle 2)
            #pragma unroll
            for (int k = 0; k < 8; ++k)
                atomicAdd(&h2[(qc[k] * G + qn[k]) << 2], hval);
            // diag (1,-1) (angle 3)
            #pragma unroll
            for (int k = 1; k < 8; ++k)
                atomicAdd(&h3[(qc[k] * G + qn[k - 1]) << 2], hval);
            if (lane > 0) atomicAdd(&h3[(qc[0] * G + pqn7) << 2], hval);

            #pragma unroll
            for (int k = 0; k < 8; ++k) qc[k] = qn[k];
        }
    }
    __syncthreads();

    // merge: thread t owns bin t of each angle; sum 8 packed halves.
    unsigned int* gh = ghist + (size_t)img * 4096;
    #pragma unroll
    for (int a = 0; a < 4; ++a) {
        const uint4 w = *reinterpret_cast<const uint4*>(&hist[a * 4096 + t * 4]);
        const unsigned int s = (w.x & 0xffffu) + (w.x >> 16)
                             + (w.y & 0xffffu) + (w.y >> 16)
                             + (w.z & 0xffffu) + (w.z >> 16)
                             + (w.w & 0xffffu) + (w.w >> 16);
        if (s) atomicAdd(&gh[a * 1024 + t], s);
    }
}

// One block per image: reduce the 3 features per angle from the merged
// global histogram; write 12 floats per image.
__global__ __launch_bounds__(1024) void glcm_feat_kernel(
    const unsigned int* __restrict__ ghist, float* __restrict__ feats)
{
    __shared__ float red[4][16][3];
    const int img = blockIdx.x;
    const int t = threadIdx.x;
    const unsigned int* gh = ghist + (size_t)img * 4096;

    const int i = t >> 5, j = t & 31;
    const int d2 = (i - j) * (i - j);
    const float inv = 1.0f / (1.0f + (float)d2);
    const int lane = t & 63, wave = t >> 6;
    #pragma unroll
    for (int a = 0; a < 4; ++a) {
        const float h  = (float)gh[a * 1024 + i * G + j];
        const float ht = (float)gh[a * 1024 + j * G + i];
        float cs = h * (float)d2;
        float hs = h * inv;
        float es = (h + ht) * (h + ht);
        #pragma unroll
        for (int off = 32; off; off >>= 1) {
            cs += __shfl_down(cs, off);
            hs += __shfl_down(hs, off);
            es += __shfl_down(es, off);
        }
        if (lane == 0) { red[a][wave][0] = cs; red[a][wave][1] = hs; red[a][wave][2] = es; }
    }
    __syncthreads();
    if (t < 4) {
        float cs = 0.f, hs = 0.f, es = 0.f;
        for (int w = 0; w < 16; ++w) {
            cs += red[t][w][0]; hs += red[t][w][1]; es += red[t][w][2];
        }
        // pair counts: (0,1):512*511, (1,1):511*511, (1,0):511*512, (1,-1):511*511
        const float Na = (t == 0 || t == 2) ? 261632.0f : 261121.0f;
        float* o = feats + img * 12 + t * 3;
        o[0] = cs / Na;                    // contrast
        o[1] = sqrtf(es) / (2.0f * Na);    // energy
        o[2] = hs / Na;                    // homogeneity
    }
}

__global__ void loss_kernel(const float* __restrict__ feats, float* __restrict__ out)
{
    const int t = threadIdx.x;  // 256 threads
    float s = 0.0f;
    for (int k = t; k < 768; k += 256)
        s += fabsf(feats[k] - feats[768 + k]);
    #pragma unroll
    for (int off = 32; off; off >>= 1) s += __shfl_down(s, off);
    __shared__ float red[4];
    if ((t & 63) == 0) red[t >> 6] = s;
    __syncthreads();
    if (t == 0) out[0] = (red[0] + red[1] + red[2] + red[3]) * (1.0f / 768.0f);
}

extern "C" void kernel_launch(void* const* d_in, const int* in_sizes, int n_in,
                              void* d_out, int out_size, void* d_ws, size_t ws_size,
                              hipStream_t stream) {
    const float* x = (const float*)d_in[0];
    const float* y = (const float*)d_in[1];
    unsigned int* ghist = (unsigned int*)d_ws;                 // 128*4096*4 = 2 MB
    float* feats = (float*)((char*)d_ws + NIMG * 4096 * 4);    // 6 KB
    float* out = (float*)d_out;

    hipMemsetAsync(ghist, 0, (size_t)NIMG * 4096 * 4, stream);
    hipLaunchKernelGGL(glcm_hist_kernel, dim3(NIMG * 4), dim3(1024), 0, stream,
                       x, y, ghist);
    hipLaunchKernelGGL(glcm_feat_kernel, dim3(NIMG), dim3(1024), 0, stream,
                       ghist, feats);
    hipLaunchKernelGGL(loss_kernel, dim3(1), dim3(256), 0, stream, feats, out);
}

// Round 6
// 52.321 us; speedup vs baseline: 63.4330x; 1.0218x over previous
//
#include <hip/hip_runtime.h>
#include <math.h>

#define G 32
#define IMG_W 512
#define IMG_H 512
#define NPIX (IMG_W * IMG_H)
#define NIMG 128
#define BAND_ROWS 128   // 4 bands per image, 512 blocks total

__device__ __forceinline__ int quantize(float v) {
    int q = (int)(v * 31.0f);   // matches (img*31).astype(int32): RN multiply, trunc convert
    return q > 31 ? 31 : q;
}

// Load 8 own pixels + 1 overlap pixel (next lane's first col) for a row.
// q[8] is valid only when lane < 63 (guarded load; avoids OOB on last image).
__device__ __forceinline__ void load_row(int* q, const float* p, int lane) {
    const float4 f0 = *reinterpret_cast<const float4*>(p);
    const float4 f1 = *reinterpret_cast<const float4*>(p + 4);
    q[0] = quantize(f0.x); q[1] = quantize(f0.y);
    q[2] = quantize(f0.z); q[3] = quantize(f0.w);
    q[4] = quantize(f1.x); q[5] = quantize(f1.y);
    q[6] = quantize(f1.z); q[7] = quantize(f1.w);
    q[8] = 0;
    if (lane < 63) q[8] = quantize(p[8]);
}

// 512 blocks = 128 images x 4 row-bands, 1024 threads (16 waves).
// Wave w owns rows [band*128 + w*8, +8); lane l owns cols [8l, 8l+8).
// Histogram: 4 angles x 1024 bins x 4 lane-copies (32-bit), 64 KB LDS.
// word = angle*4096 + bin*4 + (lane&3) -> bank = (bin%8)*4 + (lane&3):
// per 32-lane phase each copy-group is 8 lanes over 8 banks (max-load ~2).
// No shuffles: boundary pairs use the 9th overlap pixel per lane.
__global__ __launch_bounds__(1024) void glcm_hist_kernel(
    const float* __restrict__ x, const float* __restrict__ y,
    unsigned int* __restrict__ ghist)
{
    __shared__ unsigned int hist[4 * 1024 * 4];   // 64 KB

    const int blk = blockIdx.x;
    const int img = blk >> 2;
    const int band = blk & 3;
    const float* base = (img < 64) ? (x + (size_t)img * NPIX)
                                   : (y + (size_t)(img - 64) * NPIX);
    const int t = threadIdx.x;

    #pragma unroll
    for (int k = 0; k < 16; ++k) hist[t + k * 1024] = 0u;
    __syncthreads();

    const int wave = t >> 6, lane = t & 63;
    const unsigned int copy = lane & 3;
    unsigned int* h0 = hist + copy;             // angle (0,1)
    unsigned int* h1 = hist + 4096 + copy;      // angle (1,1)
    unsigned int* h2 = hist + 8192 + copy;      // angle (1,0)
    unsigned int* h3 = hist + 12288 + copy;     // angle (1,-1)

    const int r0 = band * BAND_ROWS + wave * 8;
    const float* rowp = base + (size_t)r0 * IMG_W + lane * 8;

    int qc[9];
    load_row(qc, rowp, lane);

    for (int r = r0; r < r0 + 8; ++r) {
        // angle 0: horizontal pairs (qc[k], qc[k+1]), k=0..7 (k=7 guarded)
        #pragma unroll
        for (int k = 0; k < 7; ++k)
            atomicAdd(&h0[(qc[k] * G + qc[k + 1]) << 2], 1u);
        if (lane < 63) atomicAdd(&h0[(qc[7] * G + qc[8]) << 2], 1u);

        if (r + 1 < IMG_H) {
            rowp += IMG_W;
            int qn[9];
            load_row(qn, rowp, lane);

            // angle 2 (1,0): (qc[k], qn[k]), k=0..7
            #pragma unroll
            for (int k = 0; k < 8; ++k)
                atomicAdd(&h2[(qc[k] * G + qn[k]) << 2], 1u);
            // angle 1 (1,1): (qc[k], qn[k+1]), k=0..7 (k=7 guarded, uses qn[8])
            #pragma unroll
            for (int k = 0; k < 7; ++k)
                atomicAdd(&h1[(qc[k] * G + qn[k + 1]) << 2], 1u);
            if (lane < 63) atomicAdd(&h1[(qc[7] * G + qn[8]) << 2], 1u);
            // angle 3 (1,-1): (qc[k], qn[k-1]), k=1..8 (k=8 guarded, uses qc[8])
            #pragma unroll
            for (int k = 1; k < 8; ++k)
                atomicAdd(&h3[(qc[k] * G + qn[k - 1]) << 2], 1u);
            if (lane < 63) atomicAdd(&h3[(qc[8] * G + qn[7]) << 2], 1u);

            #pragma unroll
            for (int k = 0; k < 9; ++k) qc[k] = qn[k];
        }
    }
    __syncthreads();

    // merge: thread t owns bin t of each angle; sum the 4 copies.
    unsigned int* gh = ghist + (size_t)img * 4096;
    #pragma unroll
    for (int a = 0; a < 4; ++a) {
        const uint4 w = *reinterpret_cast<const uint4*>(&hist[a * 4096 + t * 4]);
        const unsigned int s = w.x + w.y + w.z + w.w;
        if (s) atomicAdd(&gh[a * 1024 + t], s);
    }
}

// One block per image: reduce the 3 features per angle from the merged
// global histogram; write 12 floats per image.
__global__ __launch_bounds__(1024) void glcm_feat_kernel(
    const unsigned int* __restrict__ ghist, float* __restrict__ feats)
{
    __shared__ float red[4][16][3];
    const int img = blockIdx.x;
    const int t = threadIdx.x;
    const unsigned int* gh = ghist + (size_t)img * 4096;

    const int i = t >> 5, j = t & 31;
    const int d2 = (i - j) * (i - j);
    const float inv = 1.0f / (1.0f + (float)d2);
    const int lane = t & 63, wave = t >> 6;
    #pragma unroll
    for (int a = 0; a < 4; ++a) {
        const float h  = (float)gh[a * 1024 + i * G + j];
        const float ht = (float)gh[a * 1024 + j * G + i];
        float cs = h * (float)d2;
        float hs = h * inv;
        float es = (h + ht) * (h + ht);
        #pragma unroll
        for (int off = 32; off; off >>= 1) {
            cs += __shfl_down(cs, off);
            hs += __shfl_down(hs, off);
            es += __shfl_down(es, off);
        }
        if (lane == 0) { red[a][wave][0] = cs; red[a][wave][1] = hs; red[a][wave][2] = es; }
    }
    __syncthreads();
    if (t < 4) {
        float cs = 0.f, hs = 0.f, es = 0.f;
        for (int w = 0; w < 16; ++w) {
            cs += red[t][w][0]; hs += red[t][w][1]; es += red[t][w][2];
        }
        // pair counts: (0,1):512*511, (1,1):511*511, (1,0):511*512, (1,-1):511*511
        const float Na = (t == 0 || t == 2) ? 261632.0f : 261121.0f;
        float* o = feats + img * 12 + t * 3;
        o[0] = cs / Na;                    // contrast
        o[1] = sqrtf(es) / (2.0f * Na);    // energy
        o[2] = hs / Na;                    // homogeneity
    }
}

__global__ void loss_kernel(const float* __restrict__ feats, float* __restrict__ out)
{
    const int t = threadIdx.x;  // 256 threads
    float s = 0.0f;
    for (int k = t; k < 768; k += 256)
        s += fabsf(feats[k] - feats[768 + k]);
    #pragma unroll
    for (int off = 32; off; off >>= 1) s += __shfl_down(s, off);
    __shared__ float red[4];
    if ((t & 63) == 0) red[t >> 6] = s;
    __syncthreads();
    if (t == 0) out[0] = (red[0] + red[1] + red[2] + red[3]) * (1.0f / 768.0f);
}

extern "C" void kernel_launch(void* const* d_in, const int* in_sizes, int n_in,
                              void* d_out, int out_size, void* d_ws, size_t ws_size,
                              hipStream_t stream) {
    const float* x = (const float*)d_in[0];
    const float* y = (const float*)d_in[1];
    unsigned int* ghist = (unsigned int*)d_ws;                 // 128*4096*4 = 2 MB
    float* feats = (float*)((char*)d_ws + NIMG * 4096 * 4);    // 6 KB
    float* out = (float*)d_out;

    hipMemsetAsync(ghist, 0, (size_t)NIMG * 4096 * 4, stream);
    hipLaunchKernelGGL(glcm_hist_kernel, dim3(NIMG * 4), dim3(1024), 0, stream,
                       x, y, ghist);
    hipLaunchKernelGGL(glcm_feat_kernel, dim3(NIMG), dim3(1024), 0, stream,
                       ghist, feats);
    hipLaunchKernelGGL(loss_kernel, dim3(1), dim3(256), 0, stream, feats, out);
}